// Round 6
// baseline (89.491 us; speedup 1.0000x reference)
//
#include <hip/hip_runtime.h>
#include <math.h>

#define N_SPK 1024
#define M_UTT 32
#define M_ENR 16
#define M_TEST 16
#define D 512
#define N_TEST_ROWS (N_SPK * M_TEST)   // 16384

// gemm geometry: block = 512 thr (8 waves, 2 wr x 4 wc), tile 128M x 256N,
// wave = 64M x 64N (acc[4][4] -> 64 AGPR). PURE-REGISTER: no LDS, no barriers
// in the K-loop. A/B fragments global->VGPR (L2-resident), double-buffered,
// fully unrolled K (8 tiles of 64). grid = 8 x 64 = 512 blocks, XCD-swizzled.

typedef __attribute__((ext_vector_type(4))) float f32x4;
typedef __attribute__((ext_vector_type(8))) short short8;
typedef __attribute__((ext_vector_type(8))) unsigned short ushort8;

__device__ __forceinline__ unsigned short f2bf(float f) {
    unsigned int u = __float_as_uint(f);
    u += 0x7FFF + ((u >> 16) & 1);   // round-to-nearest-even
    return (unsigned short)(u >> 16);
}

// ---------------------------------------------------------------------------
// Kernel 1: centroids + test-row normalize; blocks [0,4) also zero g_row/g_pos.
// ---------------------------------------------------------------------------
__global__ __launch_bounds__(256) void prep_kernel(const float* __restrict__ emb,
                                                   unsigned short* __restrict__ cent,
                                                   unsigned short* __restrict__ test,
                                                   float* __restrict__ g_row,
                                                   float* __restrict__ g_pos) {
    const int b = blockIdx.x;
    const int tid = threadIdx.x;
    const int lane = tid & 63;
    const int wid = tid >> 6;

    if (b < 4) {   // zero the accumulators (replaces a fill dispatch)
        g_row[b * 256 + tid] = 0.f;
        g_pos[b * 256 + tid] = 0.f;
    }

    if (b < N_SPK) {
        const float* base = emb + (size_t)b * M_UTT * D;
        float a0 = 0.f, a1 = 0.f;
#pragma unroll
        for (int u = 0; u < M_ENR; ++u) {
            a0 += base[u * D + tid];
            a1 += base[u * D + tid + 256];
        }
        a0 *= (1.f / 16.f);
        a1 *= (1.f / 16.f);
        float ss = a0 * a0 + a1 * a1;
#pragma unroll
        for (int m = 1; m < 64; m <<= 1) ss += __shfl_xor(ss, m, 64);
        __shared__ float wss[4];
        if (lane == 0) wss[wid] = ss;
        __syncthreads();
        const float tot = wss[0] + wss[1] + wss[2] + wss[3];
        const float inv = 1.f / fmaxf(sqrtf(tot), 1e-8f);
        cent[b * D + tid] = f2bf(a0 * inv);
        cent[b * D + tid + 256] = f2bf(a1 * inv);
    } else {
        const int r = (b - N_SPK) * 4 + wid;   // test row 0..16383
        const int s = r >> 4, t = r & 15;
        const float* row = emb + ((size_t)s * M_UTT + M_ENR + t) * D;
        const f32x4* rv = (const f32x4*)row;
        const f32x4 v0 = rv[lane * 2];
        const f32x4 v1 = rv[lane * 2 + 1];
        float ss = v0[0]*v0[0] + v0[1]*v0[1] + v0[2]*v0[2] + v0[3]*v0[3]
                 + v1[0]*v1[0] + v1[1]*v1[1] + v1[2]*v1[2] + v1[3]*v1[3];
#pragma unroll
        for (int m = 1; m < 64; m <<= 1) ss += __shfl_xor(ss, m, 64);
        const float inv = 1.f / fmaxf(sqrtf(ss), 1e-8f);
        ushort8 o;
        o[0] = f2bf(v0[0] * inv); o[1] = f2bf(v0[1] * inv);
        o[2] = f2bf(v0[2] * inv); o[3] = f2bf(v0[3] * inv);
        o[4] = f2bf(v1[0] * inv); o[5] = f2bf(v1[1] * inv);
        o[6] = f2bf(v1[2] * inv); o[7] = f2bf(v1[3] * inv);
        *(ushort8*)&test[(size_t)r * D + lane * 8] = o;
    }
}

// ---------------------------------------------------------------------------
// Kernel 2: pure-register GEMM + fused exp/row-sum epilogue.
// ---------------------------------------------------------------------------
__global__ __launch_bounds__(512) void gemm_kernel(const unsigned short* __restrict__ A,  // cent 1024x512
                                                   const unsigned short* __restrict__ B,  // test 16384x512
                                                   const float* __restrict__ alpha_p,
                                                   const float* __restrict__ beta_p,
                                                   float* __restrict__ g_row,
                                                   float* __restrict__ g_pos) {
    __shared__ float rowsum[128];
    __shared__ float possum[128];

    const int tid = threadIdx.x;
    const int lane = tid & 63;
    const int w = tid >> 6;
    const int wr = w >> 2;           // 0..1
    const int wc = w & 3;            // 0..3

    // XCD swizzle: 512 blocks = 8 XCDs x 64; XCD owns bj in [8x, 8x+8):
    // 8 B-panels (2 MB) + A (1 MB) -> L2-resident.
    const int raw = blockIdx.x;
    const int wg = (raw & 7) * 64 + (raw >> 3);
    const int bi = wg & 7;           // 8 M-panels  (128 rows)
    const int bj = wg >> 3;          // 64 N-panels (256 cols)
    const int row0 = bi * 128, col0 = bj * 256;
    const bool has_diag = ((bj >> 3) == bi);

    const int l15 = lane & 15;
    const int h8 = (lane >> 4) * 8;  // k sub-offset 0/8/16/24

    // 8 per-lane base pointers; ALL k offsets (tile*64 + kk) fold into 13-bit imm.
    const unsigned short* pA[4];
    const unsigned short* pB[4];
#pragma unroll
    for (int mi = 0; mi < 4; ++mi)
        pA[mi] = &A[(size_t)(row0 + wr * 64 + mi * 16 + l15) * D + h8];
#pragma unroll
    for (int ni = 0; ni < 4; ++ni)
        pB[ni] = &B[(size_t)(col0 + wc * 64 + ni * 16 + l15) * D + h8];

    if (tid < 128) { rowsum[tid] = 0.f; possum[tid] = 0.f; }

    const float alpha = *alpha_p;
    const float beta = *beta_p;

    f32x4 acc[4][4] = {};
    short8 a0[4][2], b0[4][2], a1[4][2], b1[4][2];   // two frag buffers, static idx

#define LOADF(Fa, Fb, t)                                                     \
    {                                                                        \
        _Pragma("unroll") for (int mi = 0; mi < 4; ++mi) {                   \
            Fa[mi][0] = *(const short8*)(pA[mi] + (t) * 64);                 \
            Fa[mi][1] = *(const short8*)(pA[mi] + (t) * 64 + 32);            \
        }                                                                    \
        _Pragma("unroll") for (int ni = 0; ni < 4; ++ni) {                   \
            Fb[ni][0] = *(const short8*)(pB[ni] + (t) * 64);                 \
            Fb[ni][1] = *(const short8*)(pB[ni] + (t) * 64 + 32);            \
        }                                                                    \
    }

#define COMPUTE(Fa, Fb)                                                      \
    {                                                                        \
        _Pragma("unroll") for (int z = 0; z < 2; ++z)                        \
            _Pragma("unroll") for (int mi = 0; mi < 4; ++mi)                 \
                _Pragma("unroll") for (int ni = 0; ni < 4; ++ni)             \
                    acc[mi][ni] = __builtin_amdgcn_mfma_f32_16x16x32_bf16(   \
                        Fa[mi][z], Fb[ni][z], acc[mi][ni], 0, 0, 0);         \
    }

    LOADF(a0, b0, 0); LOADF(a1, b1, 1);
    COMPUTE(a0, b0);  LOADF(a0, b0, 2);
    COMPUTE(a1, b1);  LOADF(a1, b1, 3);
    COMPUTE(a0, b0);  LOADF(a0, b0, 4);
    COMPUTE(a1, b1);  LOADF(a1, b1, 5);
    COMPUTE(a0, b0);  LOADF(a0, b0, 6);
    COMPUTE(a1, b1);  LOADF(a1, b1, 7);
    COMPUTE(a0, b0);
    COMPUTE(a1, b1);
#undef LOADF
#undef COMPUTE

    // ---- epilogue: e = exp(alpha*s + beta); row totals + diagonal sums.
    // C/D layout (16x16x32): col = lane&15, row = (lane>>4)*4 + reg   [m89]
    const int bcol = col0 + wc * 64;
#pragma unroll
    for (int mi = 0; mi < 4; ++mi) {
#pragma unroll
        for (int r = 0; r < 4; ++r) {
            const int lrow = wr * 64 + mi * 16 + ((lane >> 4) << 2) + r;
            const int grow = row0 + lrow;
            float tot = 0.f, pos = 0.f;
#pragma unroll
            for (int ni = 0; ni < 4; ++ni) {
                const int gcol = bcol + ni * 16 + l15;
                const float e = __expf(fmaf(alpha, acc[mi][ni][r], beta));
                tot += e;
                if (has_diag) pos += ((gcol >> 4) == grow) ? e : 0.f;
            }
#pragma unroll
            for (int m = 1; m < 16; m <<= 1) tot += __shfl_xor(tot, m, 64);
            if (has_diag) {
#pragma unroll
                for (int m = 1; m < 16; m <<= 1) pos += __shfl_xor(pos, m, 64);
            }
            if (l15 == 0) {
                atomicAdd(&rowsum[lrow], tot);
                if (has_diag) atomicAdd(&possum[lrow], pos);
            }
        }
    }
    __syncthreads();
    if (tid < 128) {
        atomicAdd(&g_row[row0 + tid], rowsum[tid]);
        if (has_diag) atomicAdd(&g_pos[row0 + tid], possum[tid]);
    }
}

// ---------------------------------------------------------------------------
// Kernel 3: loss = mean(log(tot - pos) - log(pos)) — shfl-based, 1 barrier.
// ---------------------------------------------------------------------------
__global__ __launch_bounds__(1024) void finalize_kernel(const float* __restrict__ g_row,
                                                        const float* __restrict__ g_pos,
                                                        float* __restrict__ out) {
    __shared__ float wsum[16];
    const int i = threadIdx.x;
    const int lane = i & 63, wid = i >> 6;
    const float pos = g_pos[i];
    const float neg = g_row[i] - pos;
    float v = logf(fmaxf(neg, 1e-30f)) - logf(fmaxf(pos, 1e-30f));
#pragma unroll
    for (int m = 1; m < 64; m <<= 1) v += __shfl_xor(v, m, 64);
    if (lane == 0) wsum[wid] = v;
    __syncthreads();
    if (i < 64) {
        float s = (i < 16) ? wsum[i] : 0.f;
#pragma unroll
        for (int m = 1; m < 16; m <<= 1) s += __shfl_xor(s, m, 64);
        if (i == 0) out[0] = s * (1.f / 1024.f);
    }
}

extern "C" void kernel_launch(void* const* d_in, const int* in_sizes, int n_in,
                              void* d_out, int out_size, void* d_ws, size_t ws_size,
                              hipStream_t stream) {
    const float* emb = (const float*)d_in[0];
    // d_in[1] = labels (unused; structure fixed by construction)
    const float* alpha_p = (const float*)d_in[2];
    const float* beta_p = (const float*)d_in[3];

    unsigned short* cent = (unsigned short*)d_ws;          // 1024*512 bf16 = 1 MB
    unsigned short* test = cent + (size_t)N_SPK * D;       // 16384*512 bf16 = 16 MB
    float* g_row = (float*)(test + (size_t)N_TEST_ROWS * D);
    float* g_pos = g_row + N_SPK;

    prep_kernel<<<N_SPK + N_TEST_ROWS / 4, 256, 0, stream>>>(emb, cent, test, g_row, g_pos);

    gemm_kernel<<<512, 512, 0, stream>>>(cent, test, alpha_p, beta_p, g_row, g_pos);

    finalize_kernel<<<1, 1024, 0, stream>>>(g_row, g_pos, (float*)d_out);
}

// Round 7
// 48.580 us; speedup vs baseline: 1.8421x; 1.8421x over previous
//
#include <hip/hip_runtime.h>
#include <math.h>

#define N_SPK 1024
#define M_UTT 32
#define M_ENR 16
#define M_TEST 16
#define D 512
#define N_TEST_ROWS (N_SPK * M_TEST)   // 16384

// gemm: block = 512 thr (8 waves), tile 128M x 512N, wave = 128M x 64N.
// grid = 8 x 32 = 256 blocks = 1 per CU. A panel LDS-resident (XOR swizzle),
// B streamed L2->reg (2-ring), A-fragments software-pipelined (ping-pong
// quadrant banks loaded one phase ahead), setprio around MFMA clusters.

typedef __attribute__((ext_vector_type(4))) float f32x4;
typedef __attribute__((ext_vector_type(8))) short short8;
typedef __attribute__((ext_vector_type(8))) unsigned short ushort8;

typedef const __attribute__((address_space(1))) void g_void;
typedef __attribute__((address_space(3))) void lds_void;

__device__ __forceinline__ unsigned short f2bf(float f) {
    unsigned int u = __float_as_uint(f);
    u += 0x7FFF + ((u >> 16) & 1);   // round-to-nearest-even
    return (unsigned short)(u >> 16);
}

// ---------------------------------------------------------------------------
// Kernel 1: centroids + test-row normalize; blocks [0,4) also zero g_row/g_pos.
// ---------------------------------------------------------------------------
__global__ __launch_bounds__(256) void prep_kernel(const float* __restrict__ emb,
                                                   unsigned short* __restrict__ cent,
                                                   unsigned short* __restrict__ test,
                                                   float* __restrict__ g_row,
                                                   float* __restrict__ g_pos) {
    const int b = blockIdx.x;
    const int tid = threadIdx.x;
    const int lane = tid & 63;
    const int wid = tid >> 6;

    if (b < 4) {
        g_row[b * 256 + tid] = 0.f;
        g_pos[b * 256 + tid] = 0.f;
    }

    if (b < N_SPK) {
        const float* base = emb + (size_t)b * M_UTT * D;
        float a0 = 0.f, a1 = 0.f;
#pragma unroll
        for (int u = 0; u < M_ENR; ++u) {
            a0 += base[u * D + tid];
            a1 += base[u * D + tid + 256];
        }
        a0 *= (1.f / 16.f);
        a1 *= (1.f / 16.f);
        float ss = a0 * a0 + a1 * a1;
#pragma unroll
        for (int m = 1; m < 64; m <<= 1) ss += __shfl_xor(ss, m, 64);
        __shared__ float wss[4];
        if (lane == 0) wss[wid] = ss;
        __syncthreads();
        const float tot = wss[0] + wss[1] + wss[2] + wss[3];
        const float inv = 1.f / fmaxf(sqrtf(tot), 1e-8f);
        cent[b * D + tid] = f2bf(a0 * inv);
        cent[b * D + tid + 256] = f2bf(a1 * inv);
    } else {
        const int r = (b - N_SPK) * 4 + wid;   // test row 0..16383
        const int s = r >> 4, t = r & 15;
        const float* row = emb + ((size_t)s * M_UTT + M_ENR + t) * D;
        const f32x4* rv = (const f32x4*)row;
        const f32x4 v0 = rv[lane * 2];
        const f32x4 v1 = rv[lane * 2 + 1];
        float ss = v0[0]*v0[0] + v0[1]*v0[1] + v0[2]*v0[2] + v0[3]*v0[3]
                 + v1[0]*v1[0] + v1[1]*v1[1] + v1[2]*v1[2] + v1[3]*v1[3];
#pragma unroll
        for (int m = 1; m < 64; m <<= 1) ss += __shfl_xor(ss, m, 64);
        const float inv = 1.f / fmaxf(sqrtf(ss), 1e-8f);
        ushort8 o;
        o[0] = f2bf(v0[0] * inv); o[1] = f2bf(v0[1] * inv);
        o[2] = f2bf(v0[2] * inv); o[3] = f2bf(v0[3] * inv);
        o[4] = f2bf(v1[0] * inv); o[5] = f2bf(v1[1] * inv);
        o[6] = f2bf(v1[2] * inv); o[7] = f2bf(v1[3] * inv);
        *(ushort8*)&test[(size_t)r * D + lane * 8] = o;
    }
}

// ---------------------------------------------------------------------------
// Kernel 2: A-resident barrier-free GEMM, pipelined A-fragment quadrants.
// ---------------------------------------------------------------------------
__global__ __launch_bounds__(512, 1) void gemm_kernel(const unsigned short* __restrict__ A,  // cent 1024x512
                                                      const unsigned short* __restrict__ B,  // test 16384x512
                                                      const float* __restrict__ alpha_p,
                                                      const float* __restrict__ beta_p,
                                                      float* __restrict__ g_row,
                                                      float* __restrict__ g_pos) {
    __shared__ __align__(16) unsigned short As[128 * 512];   // 128 KB, swizzled
    __shared__ float rowsum[128];
    __shared__ float possum[128];

    const int tid = threadIdx.x;
    const int lane = tid & 63;
    const int w = tid >> 6;          // wave 0..7, owns cols [w*64, +64)

    const int raw = blockIdx.x;
    const int wg = (raw & 7) * 32 + (raw >> 3);   // XCD swizzle (8 x 32)
    const int bi = wg & 7;
    const int bj = wg >> 3;
    const int row0 = bi * 128, col0 = bj * 512;
    const bool has_diag = ((bj >> 2) == bi);

    // ---- stage A panel once: LDS[r][e] = A[row0+r][ e ^ ((r&7)<<3) ]
#pragma unroll
    for (int it = 0; it < 16; ++it) {
        const int r = it * 8 + w;
        const int src = (row0 + r) * D + ((lane * 8) ^ ((r & 7) << 3));
        __builtin_amdgcn_global_load_lds((g_void*)&A[src],
                                         (lds_void*)&As[r * D], 16, 0, 0);
    }
    if (tid < 128) { rowsum[tid] = 0.f; possum[tid] = 0.f; }

    const float alpha = *alpha_p;
    const float beta = *beta_p;

    const int bcol = col0 + w * 64;
    const int l15 = lane & 15;
    const unsigned short* bp[4];
#pragma unroll
    for (int ni = 0; ni < 4; ++ni)
        bp[ni] = &B[(size_t)(bcol + ni * 16 + l15) * D + (lane >> 4) * 8];

    // swizzled LDS read offset: (kk + (lane>>4)*8) ^ ((lane&7)<<3) = kk ^ hs
    const int hs = ((lane >> 4) * 8) ^ ((lane & 7) << 3);

    f32x4 acc[8][4] = {};
    short8 afA[4], afB[4], b0[4], b1[4];

#define LOADB(dst, kk)                                              \
    {                                                               \
        _Pragma("unroll") for (int ni = 0; ni < 4; ++ni)            \
            dst[ni] = *(const short8*)(bp[ni] + (kk));              \
    }
    // load quadrant g (mi = 4g..4g+3) fragments at k-offset kk
#define AFL(dst, kk, g)                                                        \
    {                                                                          \
        const int ofs_ = (kk) ^ hs;                                            \
        _Pragma("unroll") for (int j = 0; j < 4; ++j)                          \
            dst[j] = *(const short8*)&As[((g) * 64 + j * 16 + l15) * D + ofs_];\
    }
#define PMFMA(af, bb, g)                                                       \
    {                                                                          \
        __builtin_amdgcn_s_setprio(1);                                         \
        _Pragma("unroll") for (int j = 0; j < 4; ++j)                          \
            _Pragma("unroll") for (int ni = 0; ni < 4; ++ni)                   \
                acc[(g) * 4 + j][ni] = __builtin_amdgcn_mfma_f32_16x16x32_bf16(\
                    af[j], bb[ni], acc[(g) * 4 + j][ni], 0, 0, 0);             \
        __builtin_amdgcn_s_setprio(0);                                         \
    }
    // One 32-k half-step = 2 quadrant phases; af prefetched one phase ahead.
#define QSTEP(kk, bCur)                  \
    AFL(afB, kk, 1);                     \
    PMFMA(afA, bCur, 0);                 \
    AFL(afA, ((kk) + 32) & 511, 0);      \
    PMFMA(afB, bCur, 1);

    LOADB(b0, 0); LOADB(b1, 32);
    __syncthreads();                 // A panel staged
    AFL(afA, 0, 0);

    QSTEP(0, b0);
    LOADB(b0, 64);   QSTEP(32, b1);
    LOADB(b1, 96);   QSTEP(64, b0);
    LOADB(b0, 128);  QSTEP(96, b1);
    LOADB(b1, 160);  QSTEP(128, b0);
    LOADB(b0, 192);  QSTEP(160, b1);
    LOADB(b1, 224);  QSTEP(192, b0);
    LOADB(b0, 256);  QSTEP(224, b1);
    LOADB(b1, 288);  QSTEP(256, b0);
    LOADB(b0, 320);  QSTEP(288, b1);
    LOADB(b1, 352);  QSTEP(320, b0);
    LOADB(b0, 384);  QSTEP(352, b1);
    LOADB(b1, 416);  QSTEP(384, b0);
    LOADB(b0, 448);  QSTEP(416, b1);
    LOADB(b1, 480);  QSTEP(448, b0);
    QSTEP(480, b1);

#undef LOADB
#undef AFL
#undef PMFMA
#undef QSTEP

    // ---- epilogue: e = exp(alpha*s + beta); row totals + diagonal sums.
    // C/D layout (16x16x32): col = lane&15, row = (lane>>4)*4 + reg   [m89]
#pragma unroll
    for (int mi = 0; mi < 8; ++mi) {
#pragma unroll
        for (int r = 0; r < 4; ++r) {
            const int lrow = mi * 16 + ((lane >> 4) << 2) + r;
            const int grow = row0 + lrow;
            float tot = 0.f, pos = 0.f;
#pragma unroll
            for (int ni = 0; ni < 4; ++ni) {
                const int gcol = bcol + ni * 16 + l15;
                const float e = __expf(fmaf(alpha, acc[mi][ni][r], beta));
                tot += e;
                if (has_diag) pos += ((gcol >> 4) == grow) ? e : 0.f;
            }
#pragma unroll
            for (int m = 1; m < 16; m <<= 1) tot += __shfl_xor(tot, m, 64);
            if (has_diag) {
#pragma unroll
                for (int m = 1; m < 16; m <<= 1) pos += __shfl_xor(pos, m, 64);
            }
            if (l15 == 0) {
                atomicAdd(&rowsum[lrow], tot);
                if (has_diag) atomicAdd(&possum[lrow], pos);
            }
        }
    }
    __syncthreads();
    if (tid < 128) {
        atomicAdd(&g_row[row0 + tid], rowsum[tid]);
        if (has_diag) atomicAdd(&g_pos[row0 + tid], possum[tid]);
    }
}

// ---------------------------------------------------------------------------
// Kernel 3: loss = mean(log(tot - pos) - log(pos)) — shfl-based, 1 barrier.
// ---------------------------------------------------------------------------
__global__ __launch_bounds__(1024) void finalize_kernel(const float* __restrict__ g_row,
                                                        const float* __restrict__ g_pos,
                                                        float* __restrict__ out) {
    __shared__ float wsum[16];
    const int i = threadIdx.x;
    const int lane = i & 63, wid = i >> 6;
    const float pos = g_pos[i];
    const float neg = g_row[i] - pos;
    float v = logf(fmaxf(neg, 1e-30f)) - logf(fmaxf(pos, 1e-30f));
#pragma unroll
    for (int m = 1; m < 64; m <<= 1) v += __shfl_xor(v, m, 64);
    if (lane == 0) wsum[wid] = v;
    __syncthreads();
    if (i < 64) {
        float s = (i < 16) ? wsum[i] : 0.f;
#pragma unroll
        for (int m = 1; m < 16; m <<= 1) s += __shfl_xor(s, m, 64);
        if (i == 0) out[0] = s * (1.f / 1024.f);
    }
}

extern "C" void kernel_launch(void* const* d_in, const int* in_sizes, int n_in,
                              void* d_out, int out_size, void* d_ws, size_t ws_size,
                              hipStream_t stream) {
    const float* emb = (const float*)d_in[0];
    // d_in[1] = labels (unused; structure fixed by construction)
    const float* alpha_p = (const float*)d_in[2];
    const float* beta_p = (const float*)d_in[3];

    unsigned short* cent = (unsigned short*)d_ws;          // 1024*512 bf16 = 1 MB
    unsigned short* test = cent + (size_t)N_SPK * D;       // 16384*512 bf16 = 16 MB
    float* g_row = (float*)(test + (size_t)N_TEST_ROWS * D);
    float* g_pos = g_row + N_SPK;

    prep_kernel<<<N_SPK + N_TEST_ROWS / 4, 256, 0, stream>>>(emb, cent, test, g_row, g_pos);

    gemm_kernel<<<256, 512, 0, stream>>>(cent, test, alpha_p, beta_p, g_row, g_pos);

    finalize_kernel<<<1, 1024, 0, stream>>>(g_row, g_pos, (float*)d_out);
}